// Round 1
// baseline (1139.144 us; speedup 1.0000x reference)
//
#include <hip/hip_runtime.h>

// GCN 3-layer: h=emb[labels]; 3 × { m=(h*out_norm)[src]; agg=segsum(m,dst);
//              agg*=in_norm; h=relu?(agg@W+b) }
// Sizes fixed by the reference.
#define N_NODES 50000
#define N_EDGES 800000
#define EMB     64
#define HID     96
#define NLAB    50

__global__ void deg_kernel(const int* __restrict__ src, const int* __restrict__ dst,
                           float* __restrict__ deg_out, float* __restrict__ deg_in) {
    int i = blockIdx.x * blockDim.x + threadIdx.x;
    if (i < N_EDGES) {
        atomicAdd(&deg_out[src[i]], 1.0f);
        atomicAdd(&deg_in[dst[i]], 1.0f);
    }
}

__global__ void norm_kernel(float* __restrict__ degs, int n) {
    int i = blockIdx.x * blockDim.x + threadIdx.x;
    if (i < n) degs[i] = rsqrtf(fmaxf(degs[i], 1.0f));
}

__global__ void embed_kernel(const int* __restrict__ labels, const float* __restrict__ emb,
                             float* __restrict__ h0) {
    int i = blockIdx.x * blockDim.x + threadIdx.x;
    if (i < N_NODES * EMB) {
        int n = i >> 6, c = i & 63;
        h0[i] = emb[labels[n] * EMB + c];
    }
}

// One thread per (edge, column): gather h[src]*out_norm[src], atomic scatter to agg[dst].
template <int D>
__global__ void scatter_kernel(const float* __restrict__ h, const float* __restrict__ out_norm,
                               const int* __restrict__ src, const int* __restrict__ dst,
                               float* __restrict__ agg) {
    int i = blockIdx.x * blockDim.x + threadIdx.x;
    if (i >= N_EDGES * D) return;
    int e = i / D;
    int c = i - e * D;
    int s = src[e];
    int t = dst[e];
    atomicAdd(&agg[t * D + c], h[s * D + c] * out_norm[s]);
}

// out[n,j] = act( in_norm[n] * sum_k agg[n,k]*W[k,j] + b[j] ).  W in LDS.
template <int IN, int OUT, bool RELU>
__global__ void linear_kernel(const float* __restrict__ agg, const float* __restrict__ in_norm,
                              const float* __restrict__ W, const float* __restrict__ b,
                              float* __restrict__ out) {
    __shared__ float Ws[IN * OUT];
    __shared__ float bs[OUT];
    for (int k = threadIdx.x; k < IN * OUT; k += blockDim.x) Ws[k] = W[k];
    for (int k = threadIdx.x; k < OUT; k += blockDim.x) bs[k] = b[k];
    __syncthreads();
    int i = blockIdx.x * blockDim.x + threadIdx.x;
    if (i >= N_NODES * OUT) return;
    int n = i / OUT;
    int j = i - n * OUT;
    const float* __restrict__ row = agg + n * IN;
    float sum = 0.0f;
#pragma unroll
    for (int k = 0; k < IN; ++k) sum += row[k] * Ws[k * OUT + j];
    sum = sum * in_norm[n] + bs[j];
    out[i] = RELU ? fmaxf(sum, 0.0f) : sum;
}

static inline int cdiv(long a, int b) { return (int)((a + b - 1) / b); }

extern "C" void kernel_launch(void* const* d_in, const int* in_sizes, int n_in,
                              void* d_out, int out_size, void* d_ws, size_t ws_size,
                              hipStream_t stream) {
    const int*   dep_labels = (const int*)d_in[0];
    const int*   src        = (const int*)d_in[1];
    const int*   dst        = (const int*)d_in[2];
    const float* emb        = (const float*)d_in[3];
    const float* W1 = (const float*)d_in[4]; const float* b1 = (const float*)d_in[5];
    const float* W2 = (const float*)d_in[6]; const float* b2 = (const float*)d_in[7];
    const float* W3 = (const float*)d_in[8]; const float* b3 = (const float*)d_in[9];
    float* out = (float*)d_out;

    // Workspace layout (floats): out_norm[N] | in_norm[N] | hA[N*96] | hB[N*96] | agg[N*96]
    float* ws       = (float*)d_ws;
    float* out_norm = ws;                       // deg_out -> out_norm in place
    float* in_norm  = ws + N_NODES;             // deg_in  -> in_norm in place
    float* hA       = ws + 2 * N_NODES;
    float* hB       = hA + (size_t)N_NODES * HID;
    float* agg      = hB + (size_t)N_NODES * HID;

    const int B = 256;

    // Degrees + norms
    hipMemsetAsync(out_norm, 0, 2 * N_NODES * sizeof(float), stream);
    deg_kernel<<<cdiv(N_EDGES, B), B, 0, stream>>>(src, dst, out_norm, in_norm);
    norm_kernel<<<cdiv(2 * N_NODES, B), B, 0, stream>>>(out_norm, 2 * N_NODES);

    // h0 = emb[labels]  (stride EMB=64, stored in hA)
    embed_kernel<<<cdiv((long)N_NODES * EMB, B), B, 0, stream>>>(dep_labels, emb, hA);

    // Layer 1: EMB -> HID, relu
    hipMemsetAsync(agg, 0, (size_t)N_NODES * EMB * sizeof(float), stream);
    scatter_kernel<EMB><<<cdiv((long)N_EDGES * EMB, B), B, 0, stream>>>(hA, out_norm, src, dst, agg);
    linear_kernel<EMB, HID, true><<<cdiv((long)N_NODES * HID, B), B, 0, stream>>>(agg, in_norm, W1, b1, hB);

    // Layer 2: HID -> HID, relu
    hipMemsetAsync(agg, 0, (size_t)N_NODES * HID * sizeof(float), stream);
    scatter_kernel<HID><<<cdiv((long)N_EDGES * HID, B), B, 0, stream>>>(hB, out_norm, src, dst, agg);
    linear_kernel<HID, HID, true><<<cdiv((long)N_NODES * HID, B), B, 0, stream>>>(agg, in_norm, W2, b2, hA);

    // Layer 3: HID -> NLAB, no relu, straight to d_out
    hipMemsetAsync(agg, 0, (size_t)N_NODES * HID * sizeof(float), stream);
    scatter_kernel<HID><<<cdiv((long)N_EDGES * HID, B), B, 0, stream>>>(hA, out_norm, src, dst, agg);
    linear_kernel<HID, NLAB, false><<<cdiv((long)N_NODES * NLAB, B), B, 0, stream>>>(agg, in_norm, W3, b3, out);
}

// Round 3
// 749.344 us; speedup vs baseline: 1.5202x; 1.5202x over previous
//
#include <hip/hip_runtime.h>

// GCN 3-layer, CSR-gather formulation (no float atomics in the hot path):
//   deg/norms -> CSR by dst (histogram + scan + fill) ->
//   hs0 = emb[labels]*out_norm ->
//   L1: agg=in_norm*gather64(hs0); h1s=relu(agg@W1+b1)*out_norm
//   L2: agg=in_norm*gather96(h1s); h2s=relu(agg@W2+b2)*out_norm
//   L3: t=h2s@W3 (transform FIRST, width 50); out=in_norm*gather50(t)+b3
#define N_NODES 50000
#define N_EDGES 800000
#define EMB     64
#define HID     96
#define NLAB    50
#define NB_SCAN ((N_NODES + 255) / 256)   // 196

__global__ void deg_kernel(const int* __restrict__ src, const int* __restrict__ dst,
                           int* __restrict__ deg_out, int* __restrict__ deg_in) {
    int i = blockIdx.x * blockDim.x + threadIdx.x;
    if (i < N_EDGES) {
        atomicAdd(&deg_out[src[i]], 1);
        atomicAdd(&deg_in[dst[i]], 1);
    }
}

__global__ void norm_kernel(const int* __restrict__ deg_out, const int* __restrict__ deg_in,
                            float* __restrict__ out_norm, float* __restrict__ in_norm) {
    int i = blockIdx.x * blockDim.x + threadIdx.x;
    if (i < N_NODES) {
        out_norm[i] = rsqrtf(fmaxf((float)deg_out[i], 1.0f));
        in_norm[i]  = rsqrtf(fmaxf((float)deg_in[i], 1.0f));
    }
}

// --- 3-kernel exclusive scan of deg_in -> row_off (and wr cursor copy) ---
__global__ void scan1_kernel(const int* __restrict__ deg, int* __restrict__ bsum) {
    __shared__ int s[256];
    int t = threadIdx.x, i = blockIdx.x * 256 + t;
    s[t] = (i < N_NODES) ? deg[i] : 0;
    for (int off = 128; off > 0; off >>= 1) {
        __syncthreads();
        if (t < off) s[t] += s[t + off];
    }
    if (t == 0) bsum[blockIdx.x] = s[0];
}

__global__ void scan2_kernel(const int* __restrict__ bsum, int* __restrict__ bscan) {
    __shared__ int s[256];
    int t = threadIdx.x;
    int own = (t < NB_SCAN) ? bsum[t] : 0;
    s[t] = own;
    __syncthreads();                    // FIX: was missing — cross-wave race
    for (int off = 1; off < 256; off <<= 1) {
        int v = s[t];
        if (t >= off) v += s[t - off];
        __syncthreads();
        s[t] = v;
        __syncthreads();
    }
    if (t < NB_SCAN) bscan[t] = s[t] - own;   // exclusive
}

__global__ void scan3_kernel(const int* __restrict__ deg, const int* __restrict__ bscan,
                             int* __restrict__ row_off, int* __restrict__ wr) {
    __shared__ int s[256];
    int t = threadIdx.x, i = blockIdx.x * 256 + t;
    int own = (i < N_NODES) ? deg[i] : 0;
    s[t] = own;
    __syncthreads();                    // FIX: was missing — cross-wave race
    for (int off = 1; off < 256; off <<= 1) {
        int v = s[t];
        if (t >= off) v += s[t - off];
        __syncthreads();
        s[t] = v;
        __syncthreads();
    }
    if (i < N_NODES) {
        int ro = bscan[blockIdx.x] + s[t] - own;
        row_off[i] = ro;
        wr[i] = ro;
    }
}

__global__ void fill_kernel(const int* __restrict__ src, const int* __restrict__ dst,
                            int* __restrict__ wr, int* __restrict__ csr_src) {
    int i = blockIdx.x * blockDim.x + threadIdx.x;
    if (i < N_EDGES) {
        int r = atomicAdd(&wr[dst[i]], 1);
        csr_src[r] = src[i];
    }
}

__global__ void embed_scale_kernel(const int* __restrict__ labels, const float* __restrict__ emb,
                                   const float* __restrict__ out_norm, float* __restrict__ hs0) {
    int i = blockIdx.x * blockDim.x + threadIdx.x;
    if (i < N_NODES * EMB) {
        int n = i >> 6, c = i & 63;
        hs0[i] = emb[labels[n] * EMB + c] * out_norm[n];
    }
}

// out[n,c] = in_norm[n] * sum_{k in in(n)} hs[csr_src[k], c]  (+ bias[c])
template <int D, bool BIAS>
__global__ void gather_kernel(const float* __restrict__ hs, const int* __restrict__ row_off,
                              const int* __restrict__ deg, const int* __restrict__ csr_src,
                              const float* __restrict__ in_norm, const float* __restrict__ bias,
                              float* __restrict__ out) {
    int i = blockIdx.x * blockDim.x + threadIdx.x;
    if (i >= N_NODES * D) return;
    int n = i / D;
    int c = i - n * D;
    int k = row_off[n];
    int e = k + deg[n];
    float sum = 0.0f;
    for (; k < e; ++k) {
        int s = csr_src[k];
        sum += hs[(size_t)s * D + c];
    }
    float r = in_norm[n] * sum;
    if (BIAS) r += bias[c];
    out[i] = r;
}

// out[n,j] = act(row@W + b[j]) * post[n]   (b, post nullable)
template <int IN, int OUT, bool RELU>
__global__ void linear_kernel(const float* __restrict__ in, const float* __restrict__ W,
                              const float* __restrict__ b, const float* __restrict__ post,
                              float* __restrict__ out) {
    __shared__ float Ws[IN * OUT];
    __shared__ float bs[OUT];
    for (int k = threadIdx.x; k < IN * OUT; k += blockDim.x) Ws[k] = W[k];
    if (b) for (int k = threadIdx.x; k < OUT; k += blockDim.x) bs[k] = b[k];
    __syncthreads();
    int i = blockIdx.x * blockDim.x + threadIdx.x;
    if (i >= N_NODES * OUT) return;
    int n = i / OUT;
    int j = i - n * OUT;
    const float* __restrict__ row = in + (size_t)n * IN;
    float sum = 0.0f;
#pragma unroll
    for (int k = 0; k < IN; ++k) sum += row[k] * Ws[k * OUT + j];
    if (b) sum += bs[j];
    if (RELU) sum = fmaxf(sum, 0.0f);
    if (post) sum *= post[n];
    out[i] = sum;
}

static inline int cdiv(long a, int b) { return (int)((a + b - 1) / b); }

extern "C" void kernel_launch(void* const* d_in, const int* in_sizes, int n_in,
                              void* d_out, int out_size, void* d_ws, size_t ws_size,
                              hipStream_t stream) {
    const int*   dep_labels = (const int*)d_in[0];
    const int*   src        = (const int*)d_in[1];
    const int*   dst        = (const int*)d_in[2];
    const float* emb        = (const float*)d_in[3];
    const float* W1 = (const float*)d_in[4]; const float* b1 = (const float*)d_in[5];
    const float* W2 = (const float*)d_in[6]; const float* b2 = (const float*)d_in[7];
    const float* W3 = (const float*)d_in[8]; const float* b3 = (const float*)d_in[9];
    float* out = (float*)d_out;

    // ---- workspace layout (all 4-byte elements) ----
    int* wsp        = (int*)d_ws;
    int* deg_out_i  = wsp;                 wsp += N_NODES;
    int* deg_in_i   = wsp;                 wsp += N_NODES;
    int* row_off    = wsp;                 wsp += N_NODES;
    int* wr         = wsp;                 wsp += N_NODES;
    int* bsum       = wsp;                 wsp += 256;
    int* bscan      = wsp;                 wsp += 256;
    int* csr_src    = wsp;                 wsp += N_EDGES;
    float* out_norm = (float*)wsp;         wsp += N_NODES;
    float* in_norm  = (float*)wsp;         wsp += N_NODES;
    float* hs0      = (float*)wsp;         wsp += (size_t)N_NODES * EMB;
    float* bufA     = (float*)wsp;         wsp += (size_t)N_NODES * HID;
    float* bufB     = (float*)wsp;         // N_NODES*HID

    const int B = 256;

    // degrees + norms
    hipMemsetAsync(deg_out_i, 0, 2 * N_NODES * sizeof(int), stream);
    deg_kernel<<<cdiv(N_EDGES, B), B, 0, stream>>>(src, dst, deg_out_i, deg_in_i);
    norm_kernel<<<cdiv(N_NODES, B), B, 0, stream>>>(deg_out_i, deg_in_i, out_norm, in_norm);

    // CSR by dst
    scan1_kernel<<<NB_SCAN, 256, 0, stream>>>(deg_in_i, bsum);
    scan2_kernel<<<1, 256, 0, stream>>>(bsum, bscan);
    scan3_kernel<<<NB_SCAN, 256, 0, stream>>>(deg_in_i, bscan, row_off, wr);
    fill_kernel<<<cdiv(N_EDGES, B), B, 0, stream>>>(src, dst, wr, csr_src);

    // hs0 = emb[labels] * out_norm
    embed_scale_kernel<<<cdiv((long)N_NODES * EMB, B), B, 0, stream>>>(dep_labels, emb, out_norm, hs0);

    // Layer 1: gather64 -> linear 64->96 (relu, post-scale by out_norm)
    gather_kernel<EMB, false><<<cdiv((long)N_NODES * EMB, B), B, 0, stream>>>(
        hs0, row_off, deg_in_i, csr_src, in_norm, nullptr, bufA);
    linear_kernel<EMB, HID, true><<<cdiv((long)N_NODES * HID, B), B, 0, stream>>>(
        bufA, W1, b1, out_norm, bufB);          // bufB = h1s

    // Layer 2: gather96 -> linear 96->96 (relu, post-scale by out_norm)
    gather_kernel<HID, false><<<cdiv((long)N_NODES * HID, B), B, 0, stream>>>(
        bufB, row_off, deg_in_i, csr_src, in_norm, nullptr, bufA);
    linear_kernel<HID, HID, true><<<cdiv((long)N_NODES * HID, B), B, 0, stream>>>(
        bufA, W2, b2, out_norm, bufB);          // bufB = h2s

    // Layer 3: transform FIRST (96->50, no bias/relu/scale), then gather50 + bias
    linear_kernel<HID, NLAB, false><<<cdiv((long)N_NODES * NLAB, B), B, 0, stream>>>(
        bufB, W3, nullptr, nullptr, bufA);      // bufA = t = h2s @ W3
    gather_kernel<NLAB, true><<<cdiv((long)N_NODES * NLAB, B), B, 0, stream>>>(
        bufA, row_off, deg_in_i, csr_src, in_norm, b3, out);
}

// Round 4
// 433.809 us; speedup vs baseline: 2.6259x; 1.7274x over previous
//
#include <hip/hip_runtime.h>

// GCN 3-layer, CSR-gather + register-tiled linears:
//   deg/norms -> CSR by dst -> hs0 = emb[labels]*out_norm ->
//   L1: agg=in_norm*gather4<64>(hs0); h1s=relu(agg@W1+b1)*out_norm   [tiled]
//   L2: agg=in_norm*gather4<96>(h1s); h2s=relu(agg@W2+b2)*out_norm   [tiled]
//   L3: t=h2s@W3 (tiled, OUT padded 50->64); out=in_norm*gather2(t)+b3
#define N_NODES 50000
#define N_EDGES 800000
#define EMB     64
#define HID     96
#define NLAB    50
#define NB_SCAN ((N_NODES + 255) / 256)   // 196

__global__ void deg_kernel(const int* __restrict__ src, const int* __restrict__ dst,
                           int* __restrict__ deg_out, int* __restrict__ deg_in) {
    int i = blockIdx.x * blockDim.x + threadIdx.x;
    if (i < N_EDGES) {
        atomicAdd(&deg_out[src[i]], 1);
        atomicAdd(&deg_in[dst[i]], 1);
    }
}

__global__ void norm_kernel(const int* __restrict__ deg_out, const int* __restrict__ deg_in,
                            float* __restrict__ out_norm, float* __restrict__ in_norm) {
    int i = blockIdx.x * blockDim.x + threadIdx.x;
    if (i < N_NODES) {
        out_norm[i] = rsqrtf(fmaxf((float)deg_out[i], 1.0f));
        in_norm[i]  = rsqrtf(fmaxf((float)deg_in[i], 1.0f));
    }
}

// --- exclusive scan of deg_in -> row_off (and wr cursor copy) ---
__global__ void scan1_kernel(const int* __restrict__ deg, int* __restrict__ bsum) {
    __shared__ int s[256];
    int t = threadIdx.x, i = blockIdx.x * 256 + t;
    s[t] = (i < N_NODES) ? deg[i] : 0;
    for (int off = 128; off > 0; off >>= 1) {
        __syncthreads();
        if (t < off) s[t] += s[t + off];
    }
    if (t == 0) bsum[blockIdx.x] = s[0];
}

__global__ void scan2_kernel(const int* __restrict__ bsum, int* __restrict__ bscan) {
    __shared__ int s[256];
    int t = threadIdx.x;
    int own = (t < NB_SCAN) ? bsum[t] : 0;
    s[t] = own;
    __syncthreads();
    for (int off = 1; off < 256; off <<= 1) {
        int v = s[t];
        if (t >= off) v += s[t - off];
        __syncthreads();
        s[t] = v;
        __syncthreads();
    }
    if (t < NB_SCAN) bscan[t] = s[t] - own;   // exclusive
}

__global__ void scan3_kernel(const int* __restrict__ deg, const int* __restrict__ bscan,
                             int* __restrict__ row_off, int* __restrict__ wr) {
    __shared__ int s[256];
    int t = threadIdx.x, i = blockIdx.x * 256 + t;
    int own = (i < N_NODES) ? deg[i] : 0;
    s[t] = own;
    __syncthreads();
    for (int off = 1; off < 256; off <<= 1) {
        int v = s[t];
        if (t >= off) v += s[t - off];
        __syncthreads();
        s[t] = v;
        __syncthreads();
    }
    if (i < N_NODES) {
        int ro = bscan[blockIdx.x] + s[t] - own;
        row_off[i] = ro;
        wr[i] = ro;
    }
}

__global__ void fill_kernel(const int* __restrict__ src, const int* __restrict__ dst,
                            int* __restrict__ wr, int* __restrict__ csr_src) {
    int i = blockIdx.x * blockDim.x + threadIdx.x;
    if (i < N_EDGES) {
        int r = atomicAdd(&wr[dst[i]], 1);
        csr_src[r] = src[i];
    }
}

__global__ void embed_scale_kernel(const int* __restrict__ labels, const float* __restrict__ emb,
                                   const float* __restrict__ out_norm, float* __restrict__ hs0) {
    int i = blockIdx.x * blockDim.x + threadIdx.x;
    if (i < N_NODES * EMB) {
        int n = i >> 6, c = i & 63;
        hs0[i] = emb[labels[n] * EMB + c] * out_norm[n];
    }
}

// float4 gather: out[n, c4] = in_norm[n] * sum_{k in in(n)} hs[csr_src[k]] (vec chunk c4)
template <int D>
__global__ void gather4_kernel(const float* __restrict__ hs, const int* __restrict__ row_off,
                               const int* __restrict__ deg, const int* __restrict__ csr_src,
                               const float* __restrict__ in_norm, float* __restrict__ out) {
    constexpr int C = D / 4;
    int i = blockIdx.x * blockDim.x + threadIdx.x;
    if (i >= N_NODES * C) return;
    int n = i / C;
    int c = i - n * C;
    int k = row_off[n];
    int e = k + deg[n];
    float ax = 0.f, ay = 0.f, az = 0.f, aw = 0.f;
    for (; k + 1 < e; k += 2) {
        int s0 = csr_src[k], s1 = csr_src[k + 1];
        float4 v0 = *reinterpret_cast<const float4*>(hs + (size_t)s0 * D + c * 4);
        float4 v1 = *reinterpret_cast<const float4*>(hs + (size_t)s1 * D + c * 4);
        ax += v0.x + v1.x; ay += v0.y + v1.y; az += v0.z + v1.z; aw += v0.w + v1.w;
    }
    if (k < e) {
        int s0 = csr_src[k];
        float4 v0 = *reinterpret_cast<const float4*>(hs + (size_t)s0 * D + c * 4);
        ax += v0.x; ay += v0.y; az += v0.z; aw += v0.w;
    }
    float nn = in_norm[n];
    float4 r; r.x = ax * nn; r.y = ay * nn; r.z = az * nn; r.w = aw * nn;
    *reinterpret_cast<float4*>(out + (size_t)n * D + c * 4) = r;
}

// float2 gather for D=50 (final layer), with bias add
__global__ void gather2_kernel(const float* __restrict__ hs, const int* __restrict__ row_off,
                               const int* __restrict__ deg, const int* __restrict__ csr_src,
                               const float* __restrict__ in_norm, const float* __restrict__ bias,
                               float* __restrict__ out) {
    constexpr int D = NLAB, C = NLAB / 2;  // 25
    int i = blockIdx.x * blockDim.x + threadIdx.x;
    if (i >= N_NODES * C) return;
    int n = i / C;
    int c = i - n * C;
    int k = row_off[n];
    int e = k + deg[n];
    float ax = 0.f, ay = 0.f;
    for (; k + 1 < e; k += 2) {
        int s0 = csr_src[k], s1 = csr_src[k + 1];
        float2 v0 = *reinterpret_cast<const float2*>(hs + (size_t)s0 * D + c * 2);
        float2 v1 = *reinterpret_cast<const float2*>(hs + (size_t)s1 * D + c * 2);
        ax += v0.x + v1.x; ay += v0.y + v1.y;
    }
    if (k < e) {
        int s0 = csr_src[k];
        float2 v0 = *reinterpret_cast<const float2*>(hs + (size_t)s0 * D + c * 2);
        ax += v0.x; ay += v0.y;
    }
    float nn = in_norm[n];
    float2 r; r.x = ax * nn + bias[c * 2]; r.y = ay * nn + bias[c * 2 + 1];
    *reinterpret_cast<float2*>(out + (size_t)n * D + c * 2) = r;
}

// Register-tiled linear: block handles 64 nodes x OUTP outputs.
// Threads: 16 j-groups (NT outputs each, 16*NT == OUTP) x 16 m-groups (4 nodes each).
// out[n,j] = act(in[n,:]@W + b[j]) * post[n]   (b, post nullable)
template <int IN, int INP, int OUT, int OUTP, int NT, bool RELU>
__global__ __launch_bounds__(256) void linear_tiled(
        const float* __restrict__ in, const float* __restrict__ W,
        const float* __restrict__ b, const float* __restrict__ post,
        float* __restrict__ out) {
    __shared__ float in_s[64][INP];      // INP odd -> conflict-free column reads
    __shared__ float W_s[IN * OUTP];
    const int tid = threadIdx.x;
    const int n0 = blockIdx.x * 64;

    for (int idx = tid; idx < 64 * IN; idx += 256) {
        int m = idx / IN, k = idx - m * IN;
        int n = n0 + m;
        in_s[m][k] = (n < N_NODES) ? in[(size_t)n * IN + k] : 0.0f;
    }
    for (int idx = tid; idx < IN * OUTP; idx += 256) {
        int k = idx / OUTP, j = idx - k * OUTP;
        W_s[idx] = (j < OUT) ? W[k * OUT + j] : 0.0f;
    }
    __syncthreads();

    const int tx = tid & 15;          // j-group
    const int ty = tid >> 4;          // m-group
    const int j0 = tx * NT;
    const int m0 = ty * 4;

    float acc[4][NT];
#pragma unroll
    for (int i = 0; i < 4; ++i)
#pragma unroll
        for (int jj = 0; jj < NT; ++jj) acc[i][jj] = 0.0f;

#pragma unroll 4
    for (int k = 0; k < IN; ++k) {
        float a[4];
#pragma unroll
        for (int i = 0; i < 4; ++i) a[i] = in_s[m0 + i][k];
        float w[NT];
#pragma unroll
        for (int jj = 0; jj < NT; ++jj) w[jj] = W_s[k * OUTP + j0 + jj];
#pragma unroll
        for (int i = 0; i < 4; ++i)
#pragma unroll
            for (int jj = 0; jj < NT; ++jj) acc[i][jj] += a[i] * w[jj];
    }

#pragma unroll
    for (int i = 0; i < 4; ++i) {
        int n = n0 + m0 + i;
        if (n >= N_NODES) break;
        float pn = post ? post[n] : 1.0f;
#pragma unroll
        for (int jj = 0; jj < NT; ++jj) {
            int j = j0 + jj;
            if (j < OUT) {
                float v = acc[i][jj];
                if (b) v += b[j];
                if (RELU) v = fmaxf(v, 0.0f);
                v *= pn;
                out[(size_t)n * OUT + j] = v;
            }
        }
    }
}

static inline int cdiv(long a, int b) { return (int)((a + b - 1) / b); }

extern "C" void kernel_launch(void* const* d_in, const int* in_sizes, int n_in,
                              void* d_out, int out_size, void* d_ws, size_t ws_size,
                              hipStream_t stream) {
    const int*   dep_labels = (const int*)d_in[0];
    const int*   src        = (const int*)d_in[1];
    const int*   dst        = (const int*)d_in[2];
    const float* emb        = (const float*)d_in[3];
    const float* W1 = (const float*)d_in[4]; const float* b1 = (const float*)d_in[5];
    const float* W2 = (const float*)d_in[6]; const float* b2 = (const float*)d_in[7];
    const float* W3 = (const float*)d_in[8]; const float* b3 = (const float*)d_in[9];
    float* out = (float*)d_out;

    // ---- workspace layout (all 4-byte elements) ----
    int* wsp        = (int*)d_ws;
    int* deg_out_i  = wsp;                 wsp += N_NODES;
    int* deg_in_i   = wsp;                 wsp += N_NODES;
    int* row_off    = wsp;                 wsp += N_NODES;
    int* wr         = wsp;                 wsp += N_NODES;
    int* bsum       = wsp;                 wsp += 256;
    int* bscan      = wsp;                 wsp += 256;
    int* csr_src    = wsp;                 wsp += N_EDGES;
    float* out_norm = (float*)wsp;         wsp += N_NODES;
    float* in_norm  = (float*)wsp;         wsp += N_NODES;
    float* hs0      = (float*)wsp;         wsp += (size_t)N_NODES * EMB;
    float* bufA     = (float*)wsp;         wsp += (size_t)N_NODES * HID;
    float* bufB     = (float*)wsp;         // N_NODES*HID

    const int B = 256;
    const int NLIN = cdiv(N_NODES, 64);    // 782 blocks per linear

    // degrees + norms
    hipMemsetAsync(deg_out_i, 0, 2 * N_NODES * sizeof(int), stream);
    deg_kernel<<<cdiv(N_EDGES, B), B, 0, stream>>>(src, dst, deg_out_i, deg_in_i);
    norm_kernel<<<cdiv(N_NODES, B), B, 0, stream>>>(deg_out_i, deg_in_i, out_norm, in_norm);

    // CSR by dst
    scan1_kernel<<<NB_SCAN, 256, 0, stream>>>(deg_in_i, bsum);
    scan2_kernel<<<1, 256, 0, stream>>>(bsum, bscan);
    scan3_kernel<<<NB_SCAN, 256, 0, stream>>>(deg_in_i, bscan, row_off, wr);
    fill_kernel<<<cdiv(N_EDGES, B), B, 0, stream>>>(src, dst, wr, csr_src);

    // hs0 = emb[labels] * out_norm
    embed_scale_kernel<<<cdiv((long)N_NODES * EMB, B), B, 0, stream>>>(dep_labels, emb, out_norm, hs0);

    // Layer 1: gather4<64> -> linear 64->96 (relu, post out_norm)
    gather4_kernel<EMB><<<cdiv((long)N_NODES * (EMB / 4), B), B, 0, stream>>>(
        hs0, row_off, deg_in_i, csr_src, in_norm, bufA);
    linear_tiled<EMB, EMB + 1, HID, HID, 6, true><<<NLIN, 256, 0, stream>>>(
        bufA, W1, b1, out_norm, bufB);          // bufB = h1s

    // Layer 2: gather4<96> -> linear 96->96 (relu, post out_norm)
    gather4_kernel<HID><<<cdiv((long)N_NODES * (HID / 4), B), B, 0, stream>>>(
        bufB, row_off, deg_in_i, csr_src, in_norm, bufA);
    linear_tiled<HID, HID + 1, HID, HID, 6, true><<<NLIN, 256, 0, stream>>>(
        bufA, W2, b2, out_norm, bufB);          // bufB = h2s

    // Layer 3: transform FIRST (96->50, OUT padded to 64), then gather2 + bias
    linear_tiled<HID, HID + 1, NLAB, 64, 4, false><<<NLIN, 256, 0, stream>>>(
        bufB, W3, nullptr, nullptr, bufA);      // bufA = t = h2s @ W3 (row stride 50)
    gather2_kernel<<<cdiv((long)N_NODES * (NLAB / 2), B), B, 0, stream>>>(
        bufA, row_off, deg_in_i, csr_src, in_norm, b3, out);
}